// Round 13
// baseline (134.842 us; speedup 1.0000x reference)
//
#include <hip/hip_runtime.h>
#include <math.h>

#define HWSZ 4096   // 64*64
#define DIM  64
#define KCW  512
#define NROW 131072 // 32*4096
#define CMAX 32
#define XP   68     // x-tile pitch (floats)

typedef short bf16x8 __attribute__((ext_vector_type(8)));
typedef float f32x4  __attribute__((ext_vector_type(4)));

// ws float layout: [64..576) csq; [1024..17408) bf16 blob; [17408..19456) loss partials
#define WS_CSQ  64
#define WS_BLOB 1024
#define WS_PART 17408

static __device__ __forceinline__ unsigned short f2bf(float f) {
    union { float f; unsigned u; } v; v.f = f;
    unsigned u = v.u;
    return (unsigned short)((u + 0x7fffu + ((u >> 16) & 1u)) >> 16);  // RNE
}

// prep: exact fp32 csq, codebook -> bf16 fragment blob
// blob[((kt*2+f)*64 + l)*8 + j] = bf16(cw[kt*16 + (l&15)][f*32 + (l>>4)*8 + j])
__global__ void vq_prep_kernel(const float* __restrict__ cw, float* __restrict__ ws) {
    int tg = blockIdx.x * 256 + threadIdx.x;
    if (tg < KCW) {
        const float4* c4 = (const float4*)(cw + (size_t)tg * DIM);
        float s0 = 0.f, s1 = 0.f, s2 = 0.f, s3 = 0.f;
        #pragma unroll
        for (int i = 0; i < 16; ++i) {
            float4 c = c4[i];
            s0 = fmaf(c.x, c.x, s0); s1 = fmaf(c.y, c.y, s1);
            s2 = fmaf(c.z, c.z, s2); s3 = fmaf(c.w, c.w, s3);
        }
        ws[WS_CSQ + tg] = (s0 + s1) + (s2 + s3);
    }
    if (tg < 4096) {
        int l = tg & 63, f = (tg >> 6) & 1, kt = tg >> 7;
        int col = kt * 16 + (l & 15);
        unsigned short* blob = (unsigned short*)(ws + WS_BLOB);
        #pragma unroll
        for (int j = 0; j < 8; ++j) {
            int d = f * 32 + (l >> 4) * 8 + j;
            blob[((kt * 2 + f) * 64 + l) * 8 + j] = f2bf(cw[col * DIM + d]);
        }
    }
}

// One block = 64 rows x 512 codewords, 8 waves. Wave w holds codeword tiles
// kt=4w..4w+3 in registers. PER-WAVE thresholds (thr = wave-local row-min +
// 2*beta) make the whole scoring loop barrier-free: k* in wave w* satisfies
// s~(k*) <= m~_{w*} + 2b, so each wave's capture with the R6-proven margin is
// a correct superset. No cross-wave min, no in-loop syncthreads (R12 had 8).
__global__ __launch_bounds__(512, 4)
void vq_main_kernel(const float* __restrict__ in, const float* __restrict__ cw,
                    const float* __restrict__ ws_ro, float* __restrict__ part,
                    float* __restrict__ out) {
    __shared__ __align__(16) float xl[DIM * XP];            // 17.4 KB fp32 x-tile [d][row]
    __shared__ __align__(16) unsigned short af[8 * 64 * 8]; // 8 KB bf16 A-frags
    __shared__ float csq_l[KCW];                            // 2 KB
    __shared__ unsigned short cand[64][CMAX];               // 4 KB
    __shared__ int   cnts[64];
    __shared__ float xsqa[64];
    __shared__ float marg[64];                              // 0.0625*sqrt(xsq)+0.25
    __shared__ int   sidxl[64];
    __shared__ float redf[8];
    __shared__ int   redk[8];
    __shared__ float lossb;

    const int t  = threadIdx.x;
    const int w  = t >> 6, l = t & 63, g4 = l >> 4, cl = l & 15;
    const int b    = blockIdx.x >> 6;
    const int hw0  = (blockIdx.x & 63) * 64;
    const int row0 = blockIdx.x * 64;

    // ---- B-fragments for this wave's 4 kt-tiles (global, L3-hot, once)
    const bf16x8* __restrict__ bp = (const bf16x8*)(ws_ro + WS_BLOB);
    bf16x8 bw0[4], bw1[4];
    #pragma unroll
    for (int kt4 = 0; kt4 < 4; ++kt4) {
        const int kt = 4 * w + kt4;
        bw0[kt4] = bp[(kt * 2 + 0) * 64 + l];
        bw1[kt4] = bp[(kt * 2 + 1) * 64 + l];
    }

    // ---- stage x tile (coalesced, the only global read of x) + csq
    {
        const int tx = t & 15, ty = t >> 4;                 // ty 0..31
        const float* __restrict__ xb = in + (size_t)b * (DIM * HWSZ) + hw0;
        #pragma unroll
        for (int p = 0; p < 2; ++p) {
            int d = p * 32 + ty;
            *(float4*)(xl + d * XP + tx * 4) = *(const float4*)(xb + (size_t)d * HWSZ + tx * 4);
        }
    }
    csq_l[t] = ws_ro[WS_CSQ + t];
    if (t < 64) cnts[t] = 0;
    if (t == 0) lossb = 0.f;
    __syncthreads();                                        // xl, csq ready

    // ---- exact ||x||^2 + margin: wave 0, one row per lane (serial FMA chain,
    // column access lanes-vary-row -> 2-way bank alias = free; no shuffles).
    if (t < 64) {
        float s = 0.f;
        for (int d = 0; d < DIM; ++d) { float xv = xl[d * XP + t]; s = fmaf(xv, xv, s); }
        xsqa[t] = s;
        marg[t] = 0.0625f * sqrtf(s) + 0.25f;
    }

    // ---- build shared bf16 A-fragments once (chunk gf = t>>6)
    {
        const int gf = t >> 6, la = t & 63;
        const int row = (gf >> 1) * 16 + (la & 15);
        const int db  = (gf & 1) * 32 + (la >> 4) * 8;
        bf16x8 tmp;
        #pragma unroll
        for (int j = 0; j < 8; ++j) tmp[j] = (short)f2bf(-xl[(db + j) * XP + row]);
        *(bf16x8*)(af + t * 8) = tmp;
    }
    __syncthreads();                                        // af, xsqa, marg ready

    const bf16x8* __restrict__ afp = (const bf16x8*)af;
    float ci[4];
    #pragma unroll
    for (int kt4 = 0; kt4 < 4; ++kt4) ci[kt4] = 0.5f * csq_l[(4 * w + kt4) * 16 + cl];

    // ---- single barrier-free scoring pass: 4 row-groups x 8 MFMA each
    #pragma unroll 1
    for (int g = 0; g < 4; ++g) {
        bf16x8 a0 = afp[(g * 2 + 0) * 64 + l];
        bf16x8 a1 = afp[(g * 2 + 1) * 64 + l];
        f32x4 acc[4];
        #pragma unroll
        for (int kt4 = 0; kt4 < 4; ++kt4) {                 // 4 independent MFMA chains
            f32x4 a = {ci[kt4], ci[kt4], ci[kt4], ci[kt4]};
            a = __builtin_amdgcn_mfma_f32_16x16x32_bf16(a0, bw0[kt4], a, 0, 0, 0);
            a = __builtin_amdgcn_mfma_f32_16x16x32_bf16(a1, bw1[kt4], a, 0, 0, 0);
            acc[kt4] = a;
        }
        // wave-local per-row min over this wave's 64 cols
        float mn[4];
        #pragma unroll
        for (int rg = 0; rg < 4; ++rg)
            mn[rg] = fminf(fminf(acc[0][rg], acc[1][rg]), fminf(acc[2][rg], acc[3][rg]));
        #pragma unroll
        for (int off = 1; off < 16; off <<= 1)              // 4 chains overlap
            #pragma unroll
            for (int rg = 0; rg < 4; ++rg)
                mn[rg] = fminf(mn[rg], __shfl_xor(mn[rg], off, 64));
        // per-wave threshold (correct superset; see header comment) + insert
        #pragma unroll
        for (int rg = 0; rg < 4; ++rg) {
            const int r = g * 16 + 4 * g4 + rg;
            const float thr = mn[rg] + marg[r];
            #pragma unroll
            for (int kt4 = 0; kt4 < 4; ++kt4) {
                if (acc[kt4][rg] <= thr) {
                    int pos = atomicAdd(&cnts[r], 1);
                    if (pos < CMAX) cand[r][pos] = (unsigned short)(64 * w + kt4 * 16 + cl);
                }
            }
        }
    }
    __syncthreads();                                        // all candidates in

    // ---- exact fp32 refine: 8 slot-threads per row, x from LDS, lex tie-break
    {
        const int rr = t >> 3, slot = t & 7;
        const int n = cnts[rr];
        if (n <= CMAX) {                                    // n >= 8 (each wave's min)
            float bb = INFINITY; int bkk = 0x7fffffff;
            const float xsqe = xsqa[rr];
            for (int s = slot; s < n; s += 8) {
                int k = cand[rr][s];
                const float4* __restrict__ c4 = (const float4*)(cw + (size_t)k * DIM);
                float d0 = 0.f, d1 = 0.f, d2 = 0.f, d3 = 0.f;
                #pragma unroll
                for (int i = 0; i < 16; ++i) {
                    float4 c = c4[i];
                    d0 = fmaf(xl[(4 * i + 0) * XP + rr], c.x, d0);
                    d1 = fmaf(xl[(4 * i + 1) * XP + rr], c.y, d1);
                    d2 = fmaf(xl[(4 * i + 2) * XP + rr], c.z, d2);
                    d3 = fmaf(xl[(4 * i + 3) * XP + rr], c.w, d3);
                }
                float dot  = (d0 + d1) + (d2 + d3);
                float dist = (xsqe + csq_l[k]) - 2.f * dot;     // reference rounding order
                if (dist < bb || (dist == bb && k < bkk)) { bb = dist; bkk = k; }
            }
            #pragma unroll
            for (int off = 1; off < 8; off <<= 1) {
                float ob = __shfl_xor(bb, off, 64);
                int   ok = __shfl_xor(bkk, off, 64);
                if (ob < bb || (ob == bb && ok < bkk)) { bb = ob; bkk = ok; }
            }
            if (slot == 0) {
                sidxl[rr] = bkk;
                out[(size_t)NROW * DIM + row0 + rr] = (float)bkk;
            }
        }
    }
    __syncthreads();

    // ---- rare overflow rows: one codeword per thread, block lex-argmin
    for (int r = 0; r < 64; ++r) {
        if (cnts[r] <= CMAX) continue;                      // block-uniform
        const float xsqe = xsqa[r];
        const int k = t;                                    // 512 threads = 512 codewords
        const float4* __restrict__ c4 = (const float4*)(cw + (size_t)k * DIM);
        float d0 = 0.f, d1 = 0.f, d2 = 0.f, d3 = 0.f;
        #pragma unroll
        for (int i = 0; i < 16; ++i) {
            float4 c = c4[i];
            d0 = fmaf(xl[(4 * i + 0) * XP + r], c.x, d0);
            d1 = fmaf(xl[(4 * i + 1) * XP + r], c.y, d1);
            d2 = fmaf(xl[(4 * i + 2) * XP + r], c.z, d2);
            d3 = fmaf(xl[(4 * i + 3) * XP + r], c.w, d3);
        }
        float dot = (d0 + d1) + (d2 + d3);
        float bb  = (xsqe + csq_l[k]) - 2.f * dot;
        int  bkk  = k;
        #pragma unroll
        for (int off = 32; off; off >>= 1) {
            float ob = __shfl_down(bb, off, 64);
            int   ok = __shfl_down(bkk, off, 64);
            if (ob < bb || (ob == bb && ok < bkk)) { bb = ob; bkk = ok; }
        }
        if (l == 0) { redf[w] = bb; redk[w] = bkk; }
        __syncthreads();
        if (t == 0) {
            float fb = redf[0]; int fk = redk[0];
            for (int w2 = 1; w2 < 8; ++w2)
                if (redf[w2] < fb || (redf[w2] == fb && redk[w2] < fk)) { fb = redf[w2]; fk = redk[w2]; }
            sidxl[r] = fk;
            out[(size_t)NROW * DIM + row0 + r] = (float)fk;
        }
        __syncthreads();
    }

    // ---- epilogue: gather codeword, write quantized NCHW, loss partial (x from LDS)
    {
        const int gr = t & 63, seg = t >> 6;                // seg wave-uniform, 8 dims each
        const int kwin = sidxl[gr];
        const float* __restrict__ qp = cw + (size_t)kwin * DIM + seg * 8;
        float* __restrict__ obase = out + (size_t)b * (DIM * HWSZ) + hw0 + gr;
        float lsum = 0.f;
        #pragma unroll
        for (int dd = 0; dd < 2; ++dd) {
            float4 q4 = *(const float4*)(qp + dd * 4);
            float qv[4] = {q4.x, q4.y, q4.z, q4.w};
            #pragma unroll
            for (int c = 0; c < 4; ++c) {
                int d = seg * 8 + dd * 4 + c;
                float xv = xl[d * XP + gr];
                obase[(size_t)d * HWSZ] = qv[c];
                float diff = qv[c] - xv;
                lsum = fmaf(diff, diff, lsum);
            }
        }
        #pragma unroll
        for (int off = 32; off; off >>= 1) lsum += __shfl_down(lsum, off, 64);
        if (l == 0) atomicAdd(&lossb, lsum);
    }
    __syncthreads();
    if (t == 0) part[blockIdx.x] = lossb;
}

__global__ void vq_finalize_kernel(const float* __restrict__ part, float* __restrict__ out) {
    __shared__ float wsum[4];
    const int t = threadIdx.x;
    float s = 0.f;
    #pragma unroll
    for (int i = 0; i < 8; ++i) s += part[t * 8 + i];       // fixed order: deterministic
    #pragma unroll
    for (int off = 32; off; off >>= 1) s += __shfl_down(s, off, 64);
    if ((t & 63) == 0) wsum[t >> 6] = s;
    __syncthreads();
    if (t == 0)
        out[(size_t)NROW * DIM + NROW] =
            1.25f * ((wsum[0] + wsum[1]) + (wsum[2] + wsum[3])) / (float)((size_t)NROW * DIM);
}

extern "C" void kernel_launch(void* const* d_in, const int* in_sizes, int n_in,
                              void* d_out, int out_size, void* d_ws, size_t ws_size,
                              hipStream_t stream) {
    const float* in = (const float*)d_in[0];
    const float* cw = (const float*)d_in[1];
    float* out = (float*)d_out;
    float* ws  = (float*)d_ws;

    hipLaunchKernelGGL(vq_prep_kernel, dim3(16), dim3(256), 0, stream, cw, ws);
    hipLaunchKernelGGL(vq_main_kernel, dim3(NROW / 64), dim3(512), 0, stream,
                       in, cw, ws, ws + WS_PART, out);
    hipLaunchKernelGGL(vq_finalize_kernel, dim3(1), dim3(256), 0, stream, ws + WS_PART, out);
}

// Round 14
// 94.100 us; speedup vs baseline: 1.4330x; 1.4330x over previous
//
#include <hip/hip_runtime.h>
#include <math.h>

#define HWSZ 4096   // 64*64
#define DIM  64
#define KCW  512
#define NROW 131072 // 32*4096
#define CMAX 32
#define XP   68     // x-tile pitch (floats)

typedef short bf16x8 __attribute__((ext_vector_type(8)));
typedef float f32x4  __attribute__((ext_vector_type(4)));

// ws float layout: [64..576) csq; [1024..17408) bf16 blob; [17408..19456) loss partials
#define WS_CSQ  64
#define WS_BLOB 1024
#define WS_PART 17408

static __device__ __forceinline__ unsigned short f2bf(float f) {
    union { float f; unsigned u; } v; v.f = f;
    unsigned u = v.u;
    return (unsigned short)((u + 0x7fffu + ((u >> 16) & 1u)) >> 16);  // RNE
}

// prep: exact fp32 csq, codebook -> bf16 fragment blob
// blob[((kt*2+f)*64 + l)*8 + j] = bf16(cw[kt*16 + (l&15)][f*32 + (l>>4)*8 + j])
__global__ void vq_prep_kernel(const float* __restrict__ cw, float* __restrict__ ws) {
    int tg = blockIdx.x * 256 + threadIdx.x;
    if (tg < KCW) {
        const float4* c4 = (const float4*)(cw + (size_t)tg * DIM);
        float s0 = 0.f, s1 = 0.f, s2 = 0.f, s3 = 0.f;
        #pragma unroll
        for (int i = 0; i < 16; ++i) {
            float4 c = c4[i];
            s0 = fmaf(c.x, c.x, s0); s1 = fmaf(c.y, c.y, s1);
            s2 = fmaf(c.z, c.z, s2); s3 = fmaf(c.w, c.w, s3);
        }
        ws[WS_CSQ + tg] = (s0 + s1) + (s2 + s3);
    }
    if (tg < 4096) {
        int l = tg & 63, f = (tg >> 6) & 1, kt = tg >> 7;
        int col = kt * 16 + (l & 15);
        unsigned short* blob = (unsigned short*)(ws + WS_BLOB);
        #pragma unroll
        for (int j = 0; j < 8; ++j) {
            int d = f * 32 + (l >> 4) * 8 + j;
            blob[((kt * 2 + f) * 64 + l) * 8 + j] = f2bf(cw[col * DIM + d]);
        }
    }
}

// One block = 64 rows x 512 codewords, 8 waves; wave w holds kt=4w..4w+3 in
// registers. Scoring is BARRIER-FREE (per-wave capture, R13) but refine is
// small again (R12): waves write per-row mins to mnw[64][8] during the pass,
// ONE barrier, global thrA[r] = min_w + marg, and refine skips stored-score
// candidates above thrA before touching cw. Margin halved (f32 score storage):
// marg = 2b + eps = 0.0625*||x|| + 0.03125 (bound proof as R6).
__global__ __launch_bounds__(512, 4)
void vq_main_kernel(const float* __restrict__ in, const float* __restrict__ cw,
                    const float* __restrict__ ws_ro, float* __restrict__ part,
                    float* __restrict__ out) {
    __shared__ __align__(16) float xl[DIM * XP];            // 17.4 KB fp32 x-tile [d][row]
    __shared__ __align__(16) unsigned short af[8 * 64 * 8]; // 8 KB bf16 A-frags
    __shared__ float csq_l[KCW];                            // 2 KB
    __shared__ unsigned short cand[64][CMAX];               // 4 KB
    __shared__ float candsc[64][CMAX];                      // 8 KB f32 scores
    __shared__ float mnw[64][8];                            // 2 KB per-wave row-mins
    __shared__ float thrA[64];
    __shared__ int   cnts[64];
    __shared__ float xsqa[64];
    __shared__ float marg[64];                              // 0.0625*sqrt(xsq)+eps
    __shared__ int   sidxl[64];
    __shared__ float redf[8];
    __shared__ int   redk[8];
    __shared__ float lossb;

    const int t  = threadIdx.x;
    const int w  = t >> 6, l = t & 63, g4 = l >> 4, cl = l & 15;
    const int b    = blockIdx.x >> 6;
    const int hw0  = (blockIdx.x & 63) * 64;
    const int row0 = blockIdx.x * 64;

    // ---- B-fragments for this wave's 4 kt-tiles (global, L3-hot, once)
    const bf16x8* __restrict__ bp = (const bf16x8*)(ws_ro + WS_BLOB);
    bf16x8 bw0[4], bw1[4];
    #pragma unroll
    for (int kt4 = 0; kt4 < 4; ++kt4) {
        const int kt = 4 * w + kt4;
        bw0[kt4] = bp[(kt * 2 + 0) * 64 + l];
        bw1[kt4] = bp[(kt * 2 + 1) * 64 + l];
    }

    // ---- stage x tile (coalesced, the only global read of x) + csq
    {
        const int tx = t & 15, ty = t >> 4;                 // ty 0..31
        const float* __restrict__ xb = in + (size_t)b * (DIM * HWSZ) + hw0;
        #pragma unroll
        for (int p = 0; p < 2; ++p) {
            int d = p * 32 + ty;
            *(float4*)(xl + d * XP + tx * 4) = *(const float4*)(xb + (size_t)d * HWSZ + tx * 4);
        }
    }
    csq_l[t] = ws_ro[WS_CSQ + t];
    if (t < 64) cnts[t] = 0;
    if (t == 0) lossb = 0.f;
    __syncthreads();                                        // xl, csq ready

    // ---- exact ||x||^2 + margin: wave 0, one row per lane (2-way alias = free)
    if (t < 64) {
        float s = 0.f;
        for (int d = 0; d < DIM; ++d) { float xv = xl[d * XP + t]; s = fmaf(xv, xv, s); }
        xsqa[t] = s;
        marg[t] = 0.0625f * sqrtf(s) + 0.03125f;
    }

    // ---- build shared bf16 A-fragments once (chunk gf = t>>6)
    {
        const int gf = t >> 6, la = t & 63;
        const int row = (gf >> 1) * 16 + (la & 15);
        const int db  = (gf & 1) * 32 + (la >> 4) * 8;
        bf16x8 tmp;
        #pragma unroll
        for (int j = 0; j < 8; ++j) tmp[j] = (short)f2bf(-xl[(db + j) * XP + row]);
        *(bf16x8*)(af + t * 8) = tmp;
    }
    __syncthreads();                                        // af, xsqa, marg ready

    const bf16x8* __restrict__ afp = (const bf16x8*)af;
    float ci[4];
    #pragma unroll
    for (int kt4 = 0; kt4 < 4; ++kt4) ci[kt4] = 0.5f * csq_l[(4 * w + kt4) * 16 + cl];

    // ---- barrier-free scoring pass: 4 row-groups x 8 MFMA each
    #pragma unroll 1
    for (int g = 0; g < 4; ++g) {
        bf16x8 a0 = afp[(g * 2 + 0) * 64 + l];
        bf16x8 a1 = afp[(g * 2 + 1) * 64 + l];
        f32x4 acc[4];
        #pragma unroll
        for (int kt4 = 0; kt4 < 4; ++kt4) {                 // 4 independent MFMA chains
            f32x4 a = {ci[kt4], ci[kt4], ci[kt4], ci[kt4]};
            a = __builtin_amdgcn_mfma_f32_16x16x32_bf16(a0, bw0[kt4], a, 0, 0, 0);
            a = __builtin_amdgcn_mfma_f32_16x16x32_bf16(a1, bw1[kt4], a, 0, 0, 0);
            acc[kt4] = a;
        }
        // wave-local per-row min over this wave's 64 cols
        float mn[4];
        #pragma unroll
        for (int rg = 0; rg < 4; ++rg)
            mn[rg] = fminf(fminf(acc[0][rg], acc[1][rg]), fminf(acc[2][rg], acc[3][rg]));
        #pragma unroll
        for (int off = 1; off < 16; off <<= 1)
            #pragma unroll
            for (int rg = 0; rg < 4; ++rg)
                mn[rg] = fminf(mn[rg], __shfl_xor(mn[rg], off, 64));
        if (cl == 0) {
            #pragma unroll
            for (int rg = 0; rg < 4; ++rg) mnw[g * 16 + 4 * g4 + rg][w] = mn[rg];
        }
        // per-wave capture (superset; filtered by thrA in refine)
        #pragma unroll
        for (int rg = 0; rg < 4; ++rg) {
            const int r = g * 16 + 4 * g4 + rg;
            const float thr = mn[rg] + marg[r];
            #pragma unroll
            for (int kt4 = 0; kt4 < 4; ++kt4) {
                if (acc[kt4][rg] <= thr) {
                    int pos = atomicAdd(&cnts[r], 1);
                    if (pos < CMAX) {
                        cand[r][pos]   = (unsigned short)(64 * w + kt4 * 16 + cl);
                        candsc[r][pos] = acc[kt4][rg];
                    }
                }
            }
        }
    }
    __syncthreads();                                        // mins + candidates in

    // ---- global per-row threshold (once; R12 computed this 4x with 8 barriers)
    if (t < 64) {
        float m = mnw[t][0];
        #pragma unroll
        for (int w2 = 1; w2 < 8; ++w2) m = fminf(m, mnw[t][w2]);
        thrA[t] = m + marg[t];
    }
    __syncthreads();

    // ---- exact fp32 refine: 8 slot-threads per row, score-filtered, lex tie-break
    {
        const int rr = t >> 3, slot = t & 7;
        const int n = cnts[rr];
        if (n <= CMAX) {
            float bb = INFINITY; int bkk = 0x7fffffff;
            const float xsqe = xsqa[rr];
            const float thr  = thrA[rr];
            for (int s = slot; s < n; s += 8) {
                if (candsc[rr][s] > thr) continue;          // filtered: ~1-3 survive
                int k = cand[rr][s];
                const float4* __restrict__ c4 = (const float4*)(cw + (size_t)k * DIM);
                float d0 = 0.f, d1 = 0.f, d2 = 0.f, d3 = 0.f;
                #pragma unroll
                for (int i = 0; i < 16; ++i) {
                    float4 c = c4[i];
                    d0 = fmaf(xl[(4 * i + 0) * XP + rr], c.x, d0);
                    d1 = fmaf(xl[(4 * i + 1) * XP + rr], c.y, d1);
                    d2 = fmaf(xl[(4 * i + 2) * XP + rr], c.z, d2);
                    d3 = fmaf(xl[(4 * i + 3) * XP + rr], c.w, d3);
                }
                float dot  = (d0 + d1) + (d2 + d3);
                float dist = (xsqe + csq_l[k]) - 2.f * dot;     // reference rounding order
                if (dist < bb || (dist == bb && k < bkk)) { bb = dist; bkk = k; }
            }
            #pragma unroll
            for (int off = 1; off < 8; off <<= 1) {
                float ob = __shfl_xor(bb, off, 64);
                int   ok = __shfl_xor(bkk, off, 64);
                if (ob < bb || (ob == bb && ok < bkk)) { bb = ob; bkk = ok; }
            }
            if (slot == 0) {
                sidxl[rr] = bkk;
                out[(size_t)NROW * DIM + row0 + rr] = (float)bkk;
            }
        }
    }
    __syncthreads();

    // ---- rare overflow rows: one codeword per thread, block lex-argmin
    for (int r = 0; r < 64; ++r) {
        if (cnts[r] <= CMAX) continue;                      // block-uniform
        const float xsqe = xsqa[r];
        const int k = t;                                    // 512 threads = 512 codewords
        const float4* __restrict__ c4 = (const float4*)(cw + (size_t)k * DIM);
        float d0 = 0.f, d1 = 0.f, d2 = 0.f, d3 = 0.f;
        #pragma unroll
        for (int i = 0; i < 16; ++i) {
            float4 c = c4[i];
            d0 = fmaf(xl[(4 * i + 0) * XP + r], c.x, d0);
            d1 = fmaf(xl[(4 * i + 1) * XP + r], c.y, d1);
            d2 = fmaf(xl[(4 * i + 2) * XP + r], c.z, d2);
            d3 = fmaf(xl[(4 * i + 3) * XP + r], c.w, d3);
        }
        float dot = (d0 + d1) + (d2 + d3);
        float bb  = (xsqe + csq_l[k]) - 2.f * dot;
        int  bkk  = k;
        #pragma unroll
        for (int off = 32; off; off >>= 1) {
            float ob = __shfl_down(bb, off, 64);
            int   ok = __shfl_down(bkk, off, 64);
            if (ob < bb || (ob == bb && ok < bkk)) { bb = ob; bkk = ok; }
        }
        if (l == 0) { redf[w] = bb; redk[w] = bkk; }
        __syncthreads();
        if (t == 0) {
            float fb = redf[0]; int fk = redk[0];
            for (int w2 = 1; w2 < 8; ++w2)
                if (redf[w2] < fb || (redf[w2] == fb && redk[w2] < fk)) { fb = redf[w2]; fk = redk[w2]; }
            sidxl[r] = fk;
            out[(size_t)NROW * DIM + row0 + r] = (float)fk;
        }
        __syncthreads();
    }

    // ---- epilogue: gather codeword, write quantized NCHW, loss partial (x from LDS)
    {
        const int gr = t & 63, seg = t >> 6;                // seg wave-uniform, 8 dims each
        const int kwin = sidxl[gr];
        const float* __restrict__ qp = cw + (size_t)kwin * DIM + seg * 8;
        float* __restrict__ obase = out + (size_t)b * (DIM * HWSZ) + hw0 + gr;
        float lsum = 0.f;
        #pragma unroll
        for (int dd = 0; dd < 2; ++dd) {
            float4 q4 = *(const float4*)(qp + dd * 4);
            float qv[4] = {q4.x, q4.y, q4.z, q4.w};
            #pragma unroll
            for (int c = 0; c < 4; ++c) {
                int d = seg * 8 + dd * 4 + c;
                float xv = xl[d * XP + gr];
                obase[(size_t)d * HWSZ] = qv[c];
                float diff = qv[c] - xv;
                lsum = fmaf(diff, diff, lsum);
            }
        }
        #pragma unroll
        for (int off = 32; off; off >>= 1) lsum += __shfl_down(lsum, off, 64);
        if (l == 0) atomicAdd(&lossb, lsum);
    }
    __syncthreads();
    if (t == 0) part[blockIdx.x] = lossb;
}

__global__ void vq_finalize_kernel(const float* __restrict__ part, float* __restrict__ out) {
    __shared__ float wsum[4];
    const int t = threadIdx.x;
    float s = 0.f;
    #pragma unroll
    for (int i = 0; i < 8; ++i) s += part[t * 8 + i];       // fixed order: deterministic
    #pragma unroll
    for (int off = 32; off; off >>= 1) s += __shfl_down(s, off, 64);
    if ((t & 63) == 0) wsum[t >> 6] = s;
    __syncthreads();
    if (t == 0)
        out[(size_t)NROW * DIM + NROW] =
            1.25f * ((wsum[0] + wsum[1]) + (wsum[2] + wsum[3])) / (float)((size_t)NROW * DIM);
}

extern "C" void kernel_launch(void* const* d_in, const int* in_sizes, int n_in,
                              void* d_out, int out_size, void* d_ws, size_t ws_size,
                              hipStream_t stream) {
    const float* in = (const float*)d_in[0];
    const float* cw = (const float*)d_in[1];
    float* out = (float*)d_out;
    float* ws  = (float*)d_ws;

    hipLaunchKernelGGL(vq_prep_kernel, dim3(16), dim3(256), 0, stream, cw, ws);
    hipLaunchKernelGGL(vq_main_kernel, dim3(NROW / 64), dim3(512), 0, stream,
                       in, cw, ws, ws + WS_PART, out);
    hipLaunchKernelGGL(vq_finalize_kernel, dim3(1), dim3(256), 0, stream, ws + WS_PART, out);
}

// Round 15
// 90.619 us; speedup vs baseline: 1.4880x; 1.0384x over previous
//
#include <hip/hip_runtime.h>
#include <math.h>

#define HWSZ 4096   // 64*64
#define DIM  64
#define KCW  512
#define NROW 131072 // 32*4096
#define CMAX 16
#define XPW  17     // wave x-tile pitch (floats)
#define WVS  1280   // floats per wave LDS slice (5120 B)

typedef short bf16x8 __attribute__((ext_vector_type(8)));
typedef float f32x4  __attribute__((ext_vector_type(4)));

// ws float layout: [64..576) csq; [1024..17408) bf16 blob; [17408..25600) wave loss partials
#define WS_CSQ  64
#define WS_BLOB 1024
#define WS_PART 17408

static __device__ __forceinline__ unsigned short f2bf(float f) {
    union { float f; unsigned u; } v; v.f = f;
    unsigned u = v.u;
    return (unsigned short)((u + 0x7fffu + ((u >> 16) & 1u)) >> 16);  // RNE
}

// prep: exact fp32 csq, codebook -> bf16 fragment blob
// blob[((kt*2+f)*64 + l)*8 + j] = bf16(cw[kt*16 + (l&15)][f*32 + (l>>4)*8 + j])
__global__ void vq_prep_kernel(const float* __restrict__ cw, float* __restrict__ ws) {
    int tg = blockIdx.x * 256 + threadIdx.x;
    if (tg < KCW) {
        const float4* c4 = (const float4*)(cw + (size_t)tg * DIM);
        float s0 = 0.f, s1 = 0.f, s2 = 0.f, s3 = 0.f;
        #pragma unroll
        for (int i = 0; i < 16; ++i) {
            float4 c = c4[i];
            s0 = fmaf(c.x, c.x, s0); s1 = fmaf(c.y, c.y, s1);
            s2 = fmaf(c.z, c.z, s2); s3 = fmaf(c.w, c.w, s3);
        }
        ws[WS_CSQ + tg] = (s0 + s1) + (s2 + s3);
    }
    if (tg < 4096) {
        int l = tg & 63, f = (tg >> 6) & 1, kt = tg >> 7;
        int col = kt * 16 + (l & 15);
        unsigned short* blob = (unsigned short*)(ws + WS_BLOB);
        #pragma unroll
        for (int j = 0; j < 8; ++j) {
            int d = f * 32 + (l >> 4) * 8 + j;
            blob[((kt * 2 + f) * 64 + l) * 8 + j] = f2bf(cw[col * DIM + d]);
        }
    }
}

// ZERO-BARRIER kernel. 4 independent waves per 256-thr block; wave w owns 16
// rows and ALL 512 codewords with a private 5 KB LDS slice. Wave-local min ==
// global min, so sweep-2 capture uses the FINAL threshold (tight, ~1-3 cands)
// -- no cross-wave exchange, no __syncthreads, no convoy. 20 KB LDS/block ->
// up to 8 blocks x 4 waves = 32 waves/CU. Numerics identical to R6-R14 chain.
__global__ __launch_bounds__(256, 4)
void vq_main_kernel(const float* __restrict__ in, const float* __restrict__ cw,
                    const float* __restrict__ ws_ro, float* __restrict__ part,
                    float* __restrict__ out) {
    __shared__ float lds[4 * WVS];

    const int t  = threadIdx.x;
    const int w  = t >> 6, l = t & 63;
    const int hi = l >> 4, cl = l & 15;

    float* S     = lds + w * WVS;            // wave-private slice
    float* xw    = S;                        // [64][XPW] fp32 x-tile
    float* xsq   = S + 1088;                 // [16]
    int*   sidxp = (int*)(S + 1104);         // [16]
    int*   cntsp = (int*)(S + 1120);         // [16]
    unsigned short* candp = (unsigned short*)(S + 1136);  // [16][16]

    const int b    = blockIdx.x >> 6;
    const int hwW  = (blockIdx.x & 63) * 64 + w * 16;
    const int rowW = blockIdx.x * 64 + w * 16;

    if (l < 16) cntsp[l] = 0;

    // ---- stage this wave's 16 rows x 64 dims into LDS (coalesced 64B x4 per iter)
    const float* __restrict__ xg = in + (size_t)b * (DIM * HWSZ) + hwW;
    #pragma unroll
    for (int i = 0; i < 16; ++i) {
        int d = 4 * i + hi;
        xw[d * XPW + cl] = xg[(size_t)d * HWSZ + cl];
    }

    // ---- exact ||x||^2: serial chain per row (R12-14 rounding), lanes 0..15
    if (l < 16) {
        float s = 0.f;
        for (int d = 0; d < DIM; ++d) { float xv = xw[d * XPW + l]; s = fmaf(xv, xv, s); }
        xsq[l] = s;
    }

    // ---- A fragments bf16(-x): row = cl, d-slots hi*8+j / 32+hi*8+j
    bf16x8 a0, a1;
    #pragma unroll
    for (int j = 0; j < 8; ++j) a0[j] = (short)f2bf(-xw[(hi * 8 + j) * XPW + cl]);
    #pragma unroll
    for (int j = 0; j < 8; ++j) a1[j] = (short)f2bf(-xw[(32 + hi * 8 + j) * XPW + cl]);

    const bf16x8* __restrict__ bp   = (const bf16x8*)(ws_ro + WS_BLOB);
    const float*  __restrict__ csqg = ws_ro + WS_CSQ;

    // ---- sweep 1: running per-lane min of s = csq/2 - dot over all 32 kt
    float mn[4] = {INFINITY, INFINITY, INFINITY, INFINITY};
    #pragma unroll 2
    for (int kt = 0; kt < 32; ++kt) {
        float ci = 0.5f * csqg[kt * 16 + cl];
        f32x4 acc = {ci, ci, ci, ci};
        bf16x8 b0 = bp[(kt * 2 + 0) * 64 + l];
        bf16x8 b1 = bp[(kt * 2 + 1) * 64 + l];
        acc = __builtin_amdgcn_mfma_f32_16x16x32_bf16(a0, b0, acc, 0, 0, 0);
        acc = __builtin_amdgcn_mfma_f32_16x16x32_bf16(a1, b1, acc, 0, 0, 0);
        #pragma unroll
        for (int rg = 0; rg < 4; ++rg) mn[rg] = fminf(mn[rg], acc[rg]);
    }
    #pragma unroll
    for (int off = 1; off < 16; off <<= 1)      // row-min across 16 col-lanes: FINAL
        #pragma unroll
        for (int rg = 0; rg < 4; ++rg)
            mn[rg] = fminf(mn[rg], __shfl_xor(mn[rg], off, 64));

    // every lane computes its rows' thresholds directly (all have the reduced min)
    // marg = 2*beta + eps = 0.0625*||x|| + 0.03125 (R14-proven, f32 scores)
    float thr[4];
    #pragma unroll
    for (int rg = 0; rg < 4; ++rg)
        thr[rg] = mn[rg] + 0.0625f * sqrtf(xsq[4 * hi + rg]) + 0.03125f;

    // ---- sweep 2: recompute, capture vs FINAL threshold (tight set, ~1-3/row)
    #pragma unroll 2
    for (int kt = 0; kt < 32; ++kt) {
        float ci = 0.5f * csqg[kt * 16 + cl];
        f32x4 acc = {ci, ci, ci, ci};
        bf16x8 b0 = bp[(kt * 2 + 0) * 64 + l];
        bf16x8 b1 = bp[(kt * 2 + 1) * 64 + l];
        acc = __builtin_amdgcn_mfma_f32_16x16x32_bf16(a0, b0, acc, 0, 0, 0);
        acc = __builtin_amdgcn_mfma_f32_16x16x32_bf16(a1, b1, acc, 0, 0, 0);
        #pragma unroll
        for (int rg = 0; rg < 4; ++rg) {
            if (acc[rg] <= thr[rg]) {
                int r = 4 * hi + rg;             // wave-private row
                int pos = atomicAdd(&cntsp[r], 1);
                if (pos < CMAX) candp[r * 16 + pos] = (unsigned short)(kt * 16 + cl);
            }
        }
    }

    // ---- exact fp32 refine: 4 lanes/row, quad-sum order preserved, lex tie-break
    {
        const int r = l >> 2, q = l & 3;
        const int n = cntsp[r];
        if (n <= CMAX) {                         // n >= 1 (argmin always captured)
            float bb = INFINITY; int bkk = 0x7fffffff;
            const float xsqe = xsq[r];
            for (int s = q; s < n; s += 4) {
                int k = candp[r * 16 + s];
                const float4* __restrict__ c4 = (const float4*)(cw + (size_t)k * DIM);
                float d0 = 0.f, d1 = 0.f, d2 = 0.f, d3 = 0.f;
                #pragma unroll
                for (int i = 0; i < 16; ++i) {
                    float4 c = c4[i];
                    d0 = fmaf(xw[(4 * i + 0) * XPW + r], c.x, d0);
                    d1 = fmaf(xw[(4 * i + 1) * XPW + r], c.y, d1);
                    d2 = fmaf(xw[(4 * i + 2) * XPW + r], c.z, d2);
                    d3 = fmaf(xw[(4 * i + 3) * XPW + r], c.w, d3);
                }
                float dot  = (d0 + d1) + (d2 + d3);
                float dist = (xsqe + csqg[k]) - 2.f * dot;   // reference rounding order
                if (dist < bb || (dist == bb && k < bkk)) { bb = dist; bkk = k; }
            }
            #pragma unroll
            for (int off = 1; off < 4; off <<= 1) {
                float ob = __shfl_xor(bb, off, 64);
                int   ok = __shfl_xor(bkk, off, 64);
                if (ob < bb || (ob == bb && ok < bkk)) { bb = ob; bkk = ok; }
            }
            if (q == 0) {
                sidxp[r] = bkk;
                out[(size_t)NROW * DIM + rowW + r] = (float)bkk;
            }
        }
    }

    // ---- rare overflow rows (cnt > CMAX): wave-local exact full scan, 8 cols/lane
    for (int r = 0; r < 16; ++r) {
        if (cntsp[r] <= CMAX) continue;          // wave-uniform, deterministic count
        const float xsqe = xsq[r];
        float bb = INFINITY; int bkk = 0x7fffffff;
        for (int kk = 0; kk < 8; ++kk) {
            int k = kk * 64 + l;
            const float4* __restrict__ c4 = (const float4*)(cw + (size_t)k * DIM);
            float d0 = 0.f, d1 = 0.f, d2 = 0.f, d3 = 0.f;
            #pragma unroll
            for (int i = 0; i < 16; ++i) {
                float4 c = c4[i];
                d0 = fmaf(xw[(4 * i + 0) * XPW + r], c.x, d0);
                d1 = fmaf(xw[(4 * i + 1) * XPW + r], c.y, d1);
                d2 = fmaf(xw[(4 * i + 2) * XPW + r], c.z, d2);
                d3 = fmaf(xw[(4 * i + 3) * XPW + r], c.w, d3);
            }
            float dot  = (d0 + d1) + (d2 + d3);
            float dist = (xsqe + csqg[k]) - 2.f * dot;
            if (dist < bb || (dist == bb && k < bkk)) { bb = dist; bkk = k; }
        }
        #pragma unroll
        for (int off = 32; off; off >>= 1) {
            float ob = __shfl_down(bb, off, 64);
            int   ok = __shfl_down(bkk, off, 64);
            if (ob < bb || (ob == bb && ok < bkk)) { bb = ob; bkk = ok; }
        }
        if (l == 0) {
            sidxp[r] = bkk;
            out[(size_t)NROW * DIM + rowW + r] = (float)bkk;
        }
    }

    // ---- epilogue: gather codeword, write quantized NCHW, per-wave loss partial
    {
        const int r = l >> 2, q = l & 3;         // lane covers (row r, dim-quarter q)
        const int kwin = sidxp[r];
        const float4* __restrict__ qp = (const float4*)(cw + (size_t)kwin * DIM + q * 16);
        float* __restrict__ obase = out + (size_t)b * (DIM * HWSZ) + hwW + r;
        float lsum = 0.f;
        #pragma unroll
        for (int dd = 0; dd < 4; ++dd) {
            float4 q4 = qp[dd];
            float qv[4] = {q4.x, q4.y, q4.z, q4.w};
            #pragma unroll
            for (int c = 0; c < 4; ++c) {
                int d = q * 16 + dd * 4 + c;
                float xv = xw[d * XPW + r];
                obase[(size_t)d * HWSZ] = qv[c];
                float diff = qv[c] - xv;
                lsum = fmaf(diff, diff, lsum);
            }
        }
        #pragma unroll
        for (int off = 32; off; off >>= 1) lsum += __shfl_down(lsum, off, 64);
        if (l == 0) part[blockIdx.x * 4 + w] = lsum;
    }
}

__global__ void vq_finalize_kernel(const float* __restrict__ part, float* __restrict__ out) {
    __shared__ float wsum[4];
    const int t = threadIdx.x;
    float s = 0.f;
    #pragma unroll
    for (int i = 0; i < 32; ++i) s += part[t * 32 + i];   // fixed order: deterministic
    #pragma unroll
    for (int off = 32; off; off >>= 1) s += __shfl_down(s, off, 64);
    if ((t & 63) == 0) wsum[t >> 6] = s;
    __syncthreads();
    if (t == 0)
        out[(size_t)NROW * DIM + NROW] =
            1.25f * ((wsum[0] + wsum[1]) + (wsum[2] + wsum[3])) / (float)((size_t)NROW * DIM);
}

extern "C" void kernel_launch(void* const* d_in, const int* in_sizes, int n_in,
                              void* d_out, int out_size, void* d_ws, size_t ws_size,
                              hipStream_t stream) {
    const float* in = (const float*)d_in[0];
    const float* cw = (const float*)d_in[1];
    float* out = (float*)d_out;
    float* ws  = (float*)d_ws;

    hipLaunchKernelGGL(vq_prep_kernel, dim3(16), dim3(256), 0, stream, cw, ws);
    hipLaunchKernelGGL(vq_main_kernel, dim3(NROW / 64), dim3(256), 0, stream,
                       in, cw, ws, ws + WS_PART, out);
    hipLaunchKernelGGL(vq_finalize_kernel, dim3(1), dim3(256), 0, stream, ws + WS_PART, out);
}

// Round 16
// 89.450 us; speedup vs baseline: 1.5075x; 1.0131x over previous
//
#include <hip/hip_runtime.h>
#include <math.h>

#define HWSZ 4096   // 64*64
#define DIM  64
#define KCW  512
#define NROW 131072 // 32*4096
#define CMAX 16
#define XPW  17     // wave x-tile pitch (floats)
#define WVS  1280   // floats per wave LDS slice (5120 B)

typedef short bf16x8 __attribute__((ext_vector_type(8)));
typedef float f32x4  __attribute__((ext_vector_type(4)));

// ws float layout: [64..576) csq; [1024..17408) bf16 blob; [17408..25600) wave loss partials
#define WS_CSQ  64
#define WS_BLOB 1024
#define WS_PART 17408

static __device__ __forceinline__ unsigned short f2bf(float f) {
    union { float f; unsigned u; } v; v.f = f;
    unsigned u = v.u;
    return (unsigned short)((u + 0x7fffu + ((u >> 16) & 1u)) >> 16);  // RNE
}

// prep: exact fp32 csq, codebook -> bf16 fragment blob
// blob[((kt*2+f)*64 + l)*8 + j] = bf16(cw[kt*16 + (l&15)][f*32 + (l>>4)*8 + j])
__global__ void vq_prep_kernel(const float* __restrict__ cw, float* __restrict__ ws) {
    int tg = blockIdx.x * 256 + threadIdx.x;
    if (tg < KCW) {
        const float4* c4 = (const float4*)(cw + (size_t)tg * DIM);
        float s0 = 0.f, s1 = 0.f, s2 = 0.f, s3 = 0.f;
        #pragma unroll
        for (int i = 0; i < 16; ++i) {
            float4 c = c4[i];
            s0 = fmaf(c.x, c.x, s0); s1 = fmaf(c.y, c.y, s1);
            s2 = fmaf(c.z, c.z, s2); s3 = fmaf(c.w, c.w, s3);
        }
        ws[WS_CSQ + tg] = (s0 + s1) + (s2 + s3);
    }
    if (tg < 4096) {
        int l = tg & 63, f = (tg >> 6) & 1, kt = tg >> 7;
        int col = kt * 16 + (l & 15);
        unsigned short* blob = (unsigned short*)(ws + WS_BLOB);
        #pragma unroll
        for (int j = 0; j < 8; ++j) {
            int d = f * 32 + (l >> 4) * 8 + j;
            blob[((kt * 2 + f) * 64 + l) * 8 + j] = f2bf(cw[col * DIM + d]);
        }
    }
}

// ZERO-BARRIER kernel. 4 independent waves per 256-thr block; wave w owns 16
// rows and ALL 512 codewords with a private 5 KB LDS slice. Wave-local min ==
// global min -> sweep-2 capture uses the FINAL threshold (tight, ~1-3 cands);
// no cross-wave exchange, no __syncthreads. waves_per_eu(4,4) PINS the VGPR
// budget at 128: launch_bounds' min-only semantics let the allocator chase 8
// waves/EU with 64 regs + 64 MB of scratch spill (R15 counters). R3/R4 showed
// this attribute pair is the one allocation the backend doesn't sabotage.
__global__ __attribute__((amdgpu_flat_work_group_size(256, 256), amdgpu_waves_per_eu(4, 4)))
void vq_main_kernel(const float* __restrict__ in, const float* __restrict__ cw,
                    const float* __restrict__ ws_ro, float* __restrict__ part,
                    float* __restrict__ out) {
    __shared__ float lds[4 * WVS];

    const int t  = threadIdx.x;
    const int w  = t >> 6, l = t & 63;
    const int hi = l >> 4, cl = l & 15;

    float* S     = lds + w * WVS;            // wave-private slice
    float* xw    = S;                        // [64][XPW] fp32 x-tile
    float* xsq   = S + 1088;                 // [16]
    int*   sidxp = (int*)(S + 1104);         // [16]
    int*   cntsp = (int*)(S + 1120);         // [16]
    unsigned short* candp = (unsigned short*)(S + 1136);  // [16][16]

    const int b    = blockIdx.x >> 6;
    const int hwW  = (blockIdx.x & 63) * 64 + w * 16;
    const int rowW = blockIdx.x * 64 + w * 16;

    if (l < 16) cntsp[l] = 0;

    // ---- stage this wave's 16 rows x 64 dims into LDS (coalesced 64B x4 per iter)
    const float* __restrict__ xg = in + (size_t)b * (DIM * HWSZ) + hwW;
    #pragma unroll
    for (int i = 0; i < 16; ++i) {
        int d = 4 * i + hi;
        xw[d * XPW + cl] = xg[(size_t)d * HWSZ + cl];
    }

    // ---- exact ||x||^2: serial chain per row (R12-14 rounding), lanes 0..15
    if (l < 16) {
        float s = 0.f;
        for (int d = 0; d < DIM; ++d) { float xv = xw[d * XPW + l]; s = fmaf(xv, xv, s); }
        xsq[l] = s;
    }

    // ---- A fragments bf16(-x): row = cl, d-slots hi*8+j / 32+hi*8+j
    bf16x8 a0, a1;
    #pragma unroll
    for (int j = 0; j < 8; ++j) a0[j] = (short)f2bf(-xw[(hi * 8 + j) * XPW + cl]);
    #pragma unroll
    for (int j = 0; j < 8; ++j) a1[j] = (short)f2bf(-xw[(32 + hi * 8 + j) * XPW + cl]);

    const bf16x8* __restrict__ bp   = (const bf16x8*)(ws_ro + WS_BLOB);
    const float*  __restrict__ csqg = ws_ro + WS_CSQ;

    // ---- sweep 1: running per-lane min of s = csq/2 - dot over all 32 kt
    float mn[4] = {INFINITY, INFINITY, INFINITY, INFINITY};
    #pragma unroll 2
    for (int kt = 0; kt < 32; ++kt) {
        float ci = 0.5f * csqg[kt * 16 + cl];
        f32x4 acc = {ci, ci, ci, ci};
        bf16x8 b0 = bp[(kt * 2 + 0) * 64 + l];
        bf16x8 b1 = bp[(kt * 2 + 1) * 64 + l];
        acc = __builtin_amdgcn_mfma_f32_16x16x32_bf16(a0, b0, acc, 0, 0, 0);
        acc = __builtin_amdgcn_mfma_f32_16x16x32_bf16(a1, b1, acc, 0, 0, 0);
        #pragma unroll
        for (int rg = 0; rg < 4; ++rg) mn[rg] = fminf(mn[rg], acc[rg]);
    }
    #pragma unroll
    for (int off = 1; off < 16; off <<= 1)      // row-min across 16 col-lanes: FINAL
        #pragma unroll
        for (int rg = 0; rg < 4; ++rg)
            mn[rg] = fminf(mn[rg], __shfl_xor(mn[rg], off, 64));

    // every lane computes its rows' thresholds directly (all have the reduced min)
    // marg = 2*beta + eps = 0.0625*||x|| + 0.03125 (R14-proven, f32 scores)
    float thr[4];
    #pragma unroll
    for (int rg = 0; rg < 4; ++rg)
        thr[rg] = mn[rg] + 0.0625f * sqrtf(xsq[4 * hi + rg]) + 0.03125f;

    // ---- sweep 2: recompute, capture vs FINAL threshold (tight set, ~1-3/row)
    #pragma unroll 2
    for (int kt = 0; kt < 32; ++kt) {
        float ci = 0.5f * csqg[kt * 16 + cl];
        f32x4 acc = {ci, ci, ci, ci};
        bf16x8 b0 = bp[(kt * 2 + 0) * 64 + l];
        bf16x8 b1 = bp[(kt * 2 + 1) * 64 + l];
        acc = __builtin_amdgcn_mfma_f32_16x16x32_bf16(a0, b0, acc, 0, 0, 0);
        acc = __builtin_amdgcn_mfma_f32_16x16x32_bf16(a1, b1, acc, 0, 0, 0);
        #pragma unroll
        for (int rg = 0; rg < 4; ++rg) {
            if (acc[rg] <= thr[rg]) {
                int r = 4 * hi + rg;             // wave-private row
                int pos = atomicAdd(&cntsp[r], 1);
                if (pos < CMAX) candp[r * 16 + pos] = (unsigned short)(kt * 16 + cl);
            }
        }
    }

    // ---- exact fp32 refine: 4 lanes/row, quad-sum order preserved, lex tie-break
    {
        const int r = l >> 2, q = l & 3;
        const int n = cntsp[r];
        if (n <= CMAX) {                         // n >= 1 (argmin always captured)
            float bb = INFINITY; int bkk = 0x7fffffff;
            const float xsqe = xsq[r];
            for (int s = q; s < n; s += 4) {
                int k = candp[r * 16 + s];
                const float4* __restrict__ c4 = (const float4*)(cw + (size_t)k * DIM);
                float d0 = 0.f, d1 = 0.f, d2 = 0.f, d3 = 0.f;
                #pragma unroll
                for (int i = 0; i < 16; ++i) {
                    float4 c = c4[i];
                    d0 = fmaf(xw[(4 * i + 0) * XPW + r], c.x, d0);
                    d1 = fmaf(xw[(4 * i + 1) * XPW + r], c.y, d1);
                    d2 = fmaf(xw[(4 * i + 2) * XPW + r], c.z, d2);
                    d3 = fmaf(xw[(4 * i + 3) * XPW + r], c.w, d3);
                }
                float dot  = (d0 + d1) + (d2 + d3);
                float dist = (xsqe + csqg[k]) - 2.f * dot;   // reference rounding order
                if (dist < bb || (dist == bb && k < bkk)) { bb = dist; bkk = k; }
            }
            #pragma unroll
            for (int off = 1; off < 4; off <<= 1) {
                float ob = __shfl_xor(bb, off, 64);
                int   ok = __shfl_xor(bkk, off, 64);
                if (ob < bb || (ob == bb && ok < bkk)) { bb = ob; bkk = ok; }
            }
            if (q == 0) {
                sidxp[r] = bkk;
                out[(size_t)NROW * DIM + rowW + r] = (float)bkk;
            }
        }
    }

    // ---- rare overflow rows (cnt > CMAX): wave-local exact full scan, 8 cols/lane
    for (int r = 0; r < 16; ++r) {
        if (cntsp[r] <= CMAX) continue;          // wave-uniform, deterministic count
        const float xsqe = xsq[r];
        float bb = INFINITY; int bkk = 0x7fffffff;
        for (int kk = 0; kk < 8; ++kk) {
            int k = kk * 64 + l;
            const float4* __restrict__ c4 = (const float4*)(cw + (size_t)k * DIM);
            float d0 = 0.f, d1 = 0.f, d2 = 0.f, d3 = 0.f;
            #pragma unroll
            for (int i = 0; i < 16; ++i) {
                float4 c = c4[i];
                d0 = fmaf(xw[(4 * i + 0) * XPW + r], c.x, d0);
                d1 = fmaf(xw[(4 * i + 1) * XPW + r], c.y, d1);
                d2 = fmaf(xw[(4 * i + 2) * XPW + r], c.z, d2);
                d3 = fmaf(xw[(4 * i + 3) * XPW + r], c.w, d3);
            }
            float dot  = (d0 + d1) + (d2 + d3);
            float dist = (xsqe + csqg[k]) - 2.f * dot;
            if (dist < bb || (dist == bb && k < bkk)) { bb = dist; bkk = k; }
        }
        #pragma unroll
        for (int off = 32; off; off >>= 1) {
            float ob = __shfl_down(bb, off, 64);
            int   ok = __shfl_down(bkk, off, 64);
            if (ob < bb || (ob == bb && ok < bkk)) { bb = ob; bkk = ok; }
        }
        if (l == 0) {
            sidxp[r] = bkk;
            out[(size_t)NROW * DIM + rowW + r] = (float)bkk;
        }
    }

    // ---- epilogue: gather codeword, write quantized NCHW, per-wave loss partial
    {
        const int r = l >> 2, q = l & 3;         // lane covers (row r, dim-quarter q)
        const int kwin = sidxp[r];
        const float4* __restrict__ qp = (const float4*)(cw + (size_t)kwin * DIM + q * 16);
        float* __restrict__ obase = out + (size_t)b * (DIM * HWSZ) + hwW + r;
        float lsum = 0.f;
        #pragma unroll
        for (int dd = 0; dd < 4; ++dd) {
            float4 q4 = qp[dd];
            float qv[4] = {q4.x, q4.y, q4.z, q4.w};
            #pragma unroll
            for (int c = 0; c < 4; ++c) {
                int d = q * 16 + dd * 4 + c;
                float xv = xw[d * XPW + r];
                obase[(size_t)d * HWSZ] = qv[c];
                float diff = qv[c] - xv;
                lsum = fmaf(diff, diff, lsum);
            }
        }
        #pragma unroll
        for (int off = 32; off; off >>= 1) lsum += __shfl_down(lsum, off, 64);
        if (l == 0) part[blockIdx.x * 4 + w] = lsum;
    }
}

__global__ void vq_finalize_kernel(const float* __restrict__ part, float* __restrict__ out) {
    __shared__ float wsum[4];
    const int t = threadIdx.x;
    float s = 0.f;
    #pragma unroll
    for (int i = 0; i < 32; ++i) s += part[t * 32 + i];   // fixed order: deterministic
    #pragma unroll
    for (int off = 32; off; off >>= 1) s += __shfl_down(s, off, 64);
    if ((t & 63) == 0) wsum[t >> 6] = s;
    __syncthreads();
    if (t == 0)
        out[(size_t)NROW * DIM + NROW] =
            1.25f * ((wsum[0] + wsum[1]) + (wsum[2] + wsum[3])) / (float)((size_t)NROW * DIM);
}

extern "C" void kernel_launch(void* const* d_in, const int* in_sizes, int n_in,
                              void* d_out, int out_size, void* d_ws, size_t ws_size,
                              hipStream_t stream) {
    const float* in = (const float*)d_in[0];
    const float* cw = (const float*)d_in[1];
    float* out = (float*)d_out;
    float* ws  = (float*)d_ws;

    hipLaunchKernelGGL(vq_prep_kernel, dim3(16), dim3(256), 0, stream, cw, ws);
    hipLaunchKernelGGL(vq_main_kernel, dim3(NROW / 64), dim3(256), 0, stream,
                       in, cw, ws, ws + WS_PART, out);
    hipLaunchKernelGGL(vq_finalize_kernel, dim3(1), dim3(256), 0, stream, ws + WS_PART, out);
}

// Round 17
// 72.309 us; speedup vs baseline: 1.8648x; 1.2370x over previous
//
#include <hip/hip_runtime.h>
#include <math.h>

#define HWSZ 4096   // 64*64
#define DIM  64
#define KCW  512
#define NROW 131072 // 32*4096
#define CMAX 16
#define XPW  33     // wave x-tile pitch (floats)
#define WVS  2464   // floats per wave LDS slice

typedef short bf16x8 __attribute__((ext_vector_type(8)));
typedef float f32x4  __attribute__((ext_vector_type(4)));

// ws float layout: [64..576) csq; [1024..17408) bf16 blob; [17408..21504) wave loss partials
#define WS_CSQ  64
#define WS_BLOB 1024
#define WS_PART 17408

static __device__ __forceinline__ unsigned short f2bf(float f) {
    union { float f; unsigned u; } v; v.f = f;
    unsigned u = v.u;
    return (unsigned short)((u + 0x7fffu + ((u >> 16) & 1u)) >> 16);  // RNE
}

// prep: exact fp32 csq, codebook -> bf16 fragment blob
// blob[((kt*2+f)*64 + l)*8 + j] = bf16(cw[kt*16 + (l&15)][f*32 + (l>>4)*8 + j])
__global__ void vq_prep_kernel(const float* __restrict__ cw, float* __restrict__ ws) {
    int tg = blockIdx.x * 256 + threadIdx.x;
    if (tg < KCW) {
        const float4* c4 = (const float4*)(cw + (size_t)tg * DIM);
        float s0 = 0.f, s1 = 0.f, s2 = 0.f, s3 = 0.f;
        #pragma unroll
        for (int i = 0; i < 16; ++i) {
            float4 c = c4[i];
            s0 = fmaf(c.x, c.x, s0); s1 = fmaf(c.y, c.y, s1);
            s2 = fmaf(c.z, c.z, s2); s3 = fmaf(c.w, c.w, s3);
        }
        ws[WS_CSQ + tg] = (s0 + s1) + (s2 + s3);
    }
    if (tg < 4096) {
        int l = tg & 63, f = (tg >> 6) & 1, kt = tg >> 7;
        int col = kt * 16 + (l & 15);
        unsigned short* blob = (unsigned short*)(ws + WS_BLOB);
        #pragma unroll
        for (int j = 0; j < 8; ++j) {
            int d = f * 32 + (l >> 4) * 8 + j;
            blob[((kt * 2 + f) * 64 + l) * 8 + j] = f2bf(cw[col * DIM + d]);
        }
    }
}

// ZERO-BARRIER kernel, 32 rows/wave. 4 independent waves per 256-thr block;
// wave owns 32 CONSECUTIVE hw rows (= one full 128B line per d-row: R15/16's
// 16-row waves split every output line between two waves -> RMW + double
// eviction, WRITE 96MB) and all 512 codewords. Per kt, one B-fragment pair
// feeds TWO row-group MFMAs (4:2 MFMA:load, halves the L2 blob stream).
// Wave-local min == global min -> sweep-2 capture with final threshold.
__global__ __attribute__((amdgpu_flat_work_group_size(256, 256), amdgpu_waves_per_eu(4, 4)))
void vq_main_kernel(const float* __restrict__ in, const float* __restrict__ cw,
                    const float* __restrict__ ws_ro, float* __restrict__ part,
                    float* __restrict__ out) {
    __shared__ float lds[4 * WVS];

    const int t  = threadIdx.x;
    const int w  = t >> 6, l = t & 63;
    const int hi = l >> 4, cl = l & 15;

    float* S     = lds + w * WVS;            // wave-private slice
    float* xw    = S;                        // [64][XPW] fp32 x-tile (rows 0..31)
    float* xsq   = S + 2112;                 // [32]
    int*   sidxp = (int*)(S + 2144);         // [32]
    int*   cntsp = (int*)(S + 2176);         // [32]
    unsigned short* candp = (unsigned short*)(S + 2208);  // [32][16]

    const int b    = blockIdx.x >> 5;        // 32 blocks per image (128 rows each)
    const int hwW  = (blockIdx.x & 31) * 128 + w * 32;
    const int rowW = blockIdx.x * 128 + w * 32;

    if (l < 32) cntsp[l] = 0;

    // ---- stage this wave's 32 rows x 64 dims (full 128B lines per segment)
    const float* __restrict__ xg = in + (size_t)b * (DIM * HWSZ) + hwW;
    {
        const int dd2 = l >> 5, hw = l & 31;
        #pragma unroll
        for (int i = 0; i < 32; ++i) {
            int d = 2 * i + dd2;
            xw[d * XPW + hw] = xg[(size_t)d * HWSZ + hw];
        }
    }

    // ---- exact ||x||^2: serial chain per row (reference rounding), lanes 0..31
    if (l < 32) {
        float s = 0.f;
        for (int d = 0; d < DIM; ++d) { float xv = xw[d * XPW + l]; s = fmaf(xv, xv, s); }
        xsq[l] = s;
    }

    // ---- A fragments bf16(-x) for both 16-row groups
    bf16x8 a00, a01, a10, a11;
    #pragma unroll
    for (int j = 0; j < 8; ++j) {
        a00[j] = (short)f2bf(-xw[(hi * 8 + j) * XPW + cl]);
        a01[j] = (short)f2bf(-xw[(32 + hi * 8 + j) * XPW + cl]);
        a10[j] = (short)f2bf(-xw[(hi * 8 + j) * XPW + 16 + cl]);
        a11[j] = (short)f2bf(-xw[(32 + hi * 8 + j) * XPW + 16 + cl]);
    }

    const bf16x8* __restrict__ bp   = (const bf16x8*)(ws_ro + WS_BLOB);
    const float*  __restrict__ csqg = ws_ro + WS_CSQ;

    // ---- sweep 1: per-lane running min over all 32 kt, both row groups
    float mn0[4] = {INFINITY, INFINITY, INFINITY, INFINITY};
    float mn1[4] = {INFINITY, INFINITY, INFINITY, INFINITY};
    #pragma unroll 2
    for (int kt = 0; kt < 32; ++kt) {
        float ci = 0.5f * csqg[kt * 16 + cl];
        bf16x8 b0 = bp[(kt * 2 + 0) * 64 + l];
        bf16x8 b1 = bp[(kt * 2 + 1) * 64 + l];
        f32x4 acc0 = {ci, ci, ci, ci};
        f32x4 acc1 = {ci, ci, ci, ci};
        acc0 = __builtin_amdgcn_mfma_f32_16x16x32_bf16(a00, b0, acc0, 0, 0, 0);
        acc0 = __builtin_amdgcn_mfma_f32_16x16x32_bf16(a01, b1, acc0, 0, 0, 0);
        acc1 = __builtin_amdgcn_mfma_f32_16x16x32_bf16(a10, b0, acc1, 0, 0, 0);
        acc1 = __builtin_amdgcn_mfma_f32_16x16x32_bf16(a11, b1, acc1, 0, 0, 0);
        #pragma unroll
        for (int rg = 0; rg < 4; ++rg) {
            mn0[rg] = fminf(mn0[rg], acc0[rg]);
            mn1[rg] = fminf(mn1[rg], acc1[rg]);
        }
    }
    #pragma unroll
    for (int off = 1; off < 16; off <<= 1)      // row-min across 16 col-lanes: FINAL
        #pragma unroll
        for (int rg = 0; rg < 4; ++rg) {
            mn0[rg] = fminf(mn0[rg], __shfl_xor(mn0[rg], off, 64));
            mn1[rg] = fminf(mn1[rg], __shfl_xor(mn1[rg], off, 64));
        }

    // thresholds: marg = 2*beta + eps = 0.0625*||x|| + 0.03125 (R14-proven)
    float thr0[4], thr1[4];
    #pragma unroll
    for (int rg = 0; rg < 4; ++rg) {
        thr0[rg] = mn0[rg] + 0.0625f * sqrtf(xsq[4 * hi + rg]) + 0.03125f;
        thr1[rg] = mn1[rg] + 0.0625f * sqrtf(xsq[16 + 4 * hi + rg]) + 0.03125f;
    }

    // ---- sweep 2: recompute, capture vs FINAL threshold (tight set, ~1-3/row)
    #pragma unroll 2
    for (int kt = 0; kt < 32; ++kt) {
        float ci = 0.5f * csqg[kt * 16 + cl];
        bf16x8 b0 = bp[(kt * 2 + 0) * 64 + l];
        bf16x8 b1 = bp[(kt * 2 + 1) * 64 + l];
        f32x4 acc0 = {ci, ci, ci, ci};
        f32x4 acc1 = {ci, ci, ci, ci};
        acc0 = __builtin_amdgcn_mfma_f32_16x16x32_bf16(a00, b0, acc0, 0, 0, 0);
        acc0 = __builtin_amdgcn_mfma_f32_16x16x32_bf16(a01, b1, acc0, 0, 0, 0);
        acc1 = __builtin_amdgcn_mfma_f32_16x16x32_bf16(a10, b0, acc1, 0, 0, 0);
        acc1 = __builtin_amdgcn_mfma_f32_16x16x32_bf16(a11, b1, acc1, 0, 0, 0);
        #pragma unroll
        for (int rg = 0; rg < 4; ++rg) {
            if (acc0[rg] <= thr0[rg]) {
                int r = 4 * hi + rg;
                int pos = atomicAdd(&cntsp[r], 1);
                if (pos < CMAX) candp[r * 16 + pos] = (unsigned short)(kt * 16 + cl);
            }
            if (acc1[rg] <= thr1[rg]) {
                int r = 16 + 4 * hi + rg;
                int pos = atomicAdd(&cntsp[r], 1);
                if (pos < CMAX) candp[r * 16 + pos] = (unsigned short)(kt * 16 + cl);
            }
        }
    }

    // ---- exact fp32 refine: 2 lanes/row, quad-sum order preserved, lex tie-break
    {
        const int r = l >> 1, q = l & 1;
        const int n = cntsp[r];
        if (n <= CMAX) {                         // n >= 1 (argmin always captured)
            float bb = INFINITY; int bkk = 0x7fffffff;
            const float xsqe = xsq[r];
            for (int s = q; s < n; s += 2) {
                int k = candp[r * 16 + s];
                const float4* __restrict__ c4 = (const float4*)(cw + (size_t)k * DIM);
                float d0 = 0.f, d1 = 0.f, d2 = 0.f, d3 = 0.f;
                #pragma unroll
                for (int i = 0; i < 16; ++i) {
                    float4 c = c4[i];
                    d0 = fmaf(xw[(4 * i + 0) * XPW + r], c.x, d0);
                    d1 = fmaf(xw[(4 * i + 1) * XPW + r], c.y, d1);
                    d2 = fmaf(xw[(4 * i + 2) * XPW + r], c.z, d2);
                    d3 = fmaf(xw[(4 * i + 3) * XPW + r], c.w, d3);
                }
                float dot  = (d0 + d1) + (d2 + d3);
                float dist = (xsqe + csqg[k]) - 2.f * dot;   // reference rounding order
                if (dist < bb || (dist == bb && k < bkk)) { bb = dist; bkk = k; }
            }
            {
                float ob = __shfl_xor(bb, 1, 64);
                int   ok = __shfl_xor(bkk, 1, 64);
                if (ob < bb || (ob == bb && ok < bkk)) { bb = ob; bkk = ok; }
            }
            if (q == 0) {
                sidxp[r] = bkk;
                out[(size_t)NROW * DIM + rowW + r] = (float)bkk;
            }
        }
    }

    // ---- rare overflow rows (cnt > CMAX): wave-local exact full scan, 8 cols/lane
    for (int r = 0; r < 32; ++r) {
        if (cntsp[r] <= CMAX) continue;          // wave-uniform, deterministic count
        const float xsqe = xsq[r];
        float bb = INFINITY; int bkk = 0x7fffffff;
        for (int kk = 0; kk < 8; ++kk) {
            int k = kk * 64 + l;
            const float4* __restrict__ c4 = (const float4*)(cw + (size_t)k * DIM);
            float d0 = 0.f, d1 = 0.f, d2 = 0.f, d3 = 0.f;
            #pragma unroll
            for (int i = 0; i < 16; ++i) {
                float4 c = c4[i];
                d0 = fmaf(xw[(4 * i + 0) * XPW + r], c.x, d0);
                d1 = fmaf(xw[(4 * i + 1) * XPW + r], c.y, d1);
                d2 = fmaf(xw[(4 * i + 2) * XPW + r], c.z, d2);
                d3 = fmaf(xw[(4 * i + 3) * XPW + r], c.w, d3);
            }
            float dot  = (d0 + d1) + (d2 + d3);
            float dist = (xsqe + csqg[k]) - 2.f * dot;
            if (dist < bb || (dist == bb && k < bkk)) { bb = dist; bkk = k; }
        }
        #pragma unroll
        for (int off = 32; off; off >>= 1) {
            float ob = __shfl_down(bb, off, 64);
            int   ok = __shfl_down(bkk, off, 64);
            if (ob < bb || (ob == bb && ok < bkk)) { bb = ob; bkk = ok; }
        }
        if (l == 0) {
            sidxp[r] = bkk;
            out[(size_t)NROW * DIM + rowW + r] = (float)bkk;
        }
    }

    // ---- epilogue: gather codeword, write quantized NCHW (full 128B lines), loss
    {
        const int r = l >> 1, q2 = l & 1;        // lane: row r, dim-half q2 (32 dims)
        const int kwin = sidxp[r];
        const float4* __restrict__ qp = (const float4*)(cw + (size_t)kwin * DIM + q2 * 32);
        float* __restrict__ obase = out + (size_t)b * (DIM * HWSZ) + hwW + r;
        float lsum = 0.f;
        #pragma unroll
        for (int dd = 0; dd < 8; ++dd) {
            float4 q4 = qp[dd];
            float qv[4] = {q4.x, q4.y, q4.z, q4.w};
            #pragma unroll
            for (int c = 0; c < 4; ++c) {
                int d = q2 * 32 + dd * 4 + c;
                float xv = xw[d * XPW + r];
                obase[(size_t)d * HWSZ] = qv[c];
                float diff = qv[c] - xv;
                lsum = fmaf(diff, diff, lsum);
            }
        }
        #pragma unroll
        for (int off = 32; off; off >>= 1) lsum += __shfl_down(lsum, off, 64);
        if (l == 0) part[blockIdx.x * 4 + w] = lsum;
    }
}

__global__ void vq_finalize_kernel(const float* __restrict__ part, float* __restrict__ out) {
    __shared__ float wsum[4];
    const int t = threadIdx.x;
    float s = 0.f;
    #pragma unroll
    for (int i = 0; i < 16; ++i) s += part[t * 16 + i];   // 4096 partials, fixed order
    #pragma unroll
    for (int off = 32; off; off >>= 1) s += __shfl_down(s, off, 64);
    if ((t & 63) == 0) wsum[t >> 6] = s;
    __syncthreads();
    if (t == 0)
        out[(size_t)NROW * DIM + NROW] =
            1.25f * ((wsum[0] + wsum[1]) + (wsum[2] + wsum[3])) / (float)((size_t)NROW * DIM);
}

extern "C" void kernel_launch(void* const* d_in, const int* in_sizes, int n_in,
                              void* d_out, int out_size, void* d_ws, size_t ws_size,
                              hipStream_t stream) {
    const float* in = (const float*)d_in[0];
    const float* cw = (const float*)d_in[1];
    float* out = (float*)d_out;
    float* ws  = (float*)d_ws;

    hipLaunchKernelGGL(vq_prep_kernel, dim3(16), dim3(256), 0, stream, cw, ws);
    hipLaunchKernelGGL(vq_main_kernel, dim3(NROW / 128), dim3(256), 0, stream,
                       in, cw, ws, ws + WS_PART, out);
    hipLaunchKernelGGL(vq_finalize_kernel, dim3(1), dim3(256), 0, stream, ws + WS_PART, out);
}